// Round 1
// baseline (865.325 us; speedup 1.0000x reference)
//
#include <hip/hip_runtime.h>

typedef unsigned short u16;
typedef unsigned int u32;
typedef __attribute__((ext_vector_type(8))) short bf16x8;
typedef __attribute__((ext_vector_type(4))) float f32x4;

// ---------- helpers ----------
__device__ __forceinline__ u16 f2b(float f) {           // fp32 -> bf16 RNE
  u32 u = __float_as_uint(f);
  u32 r = (u + 0x7fffu + ((u >> 16) & 1u)) >> 16;
  return (u16)r;
}
__device__ __forceinline__ float b2f(u16 b) {
  return __uint_as_float(((u32)b) << 16);
}

typedef const __attribute__((address_space(1))) unsigned int gas_u32;
typedef __attribute__((address_space(3))) unsigned int las_u32;
__device__ __forceinline__ void gload_lds16(const void* g, const void* l) {
  // global -> LDS direct DMA, 16B per lane; LDS dest is wave-uniform base + lane*16
  __builtin_amdgcn_global_load_lds((gas_u32*)(unsigned long long)g,
                                   (las_u32*)(unsigned long long)l, 16, 0, 0);
}

// ---------- cast fp32 -> bf16 (vectorized, 8 elems/thread) ----------
__global__ __launch_bounds__(256) void cast_f32_bf16(const float* __restrict__ in,
                                                     u16* __restrict__ out, int n) {
  int i = (blockIdx.x * 256 + threadIdx.x) * 8;
  if (i >= n) return;
  float4 a = *(const float4*)(in + i);
  float4 b = *(const float4*)(in + i + 4);
  bf16x8 r;
  r[0] = (short)f2b(a.x); r[1] = (short)f2b(a.y);
  r[2] = (short)f2b(a.z); r[3] = (short)f2b(a.w);
  r[4] = (short)f2b(b.x); r[5] = (short)f2b(b.y);
  r[6] = (short)f2b(b.z); r[7] = (short)f2b(b.w);
  *(bf16x8*)(out + i) = r;
}

// ---------- transpose v: qkv[b*4096+t][2048+d] -> vT[b][d][t] ----------
__global__ __launch_bounds__(256) void transpose_v(const u16* __restrict__ qkv,
                                                   u16* __restrict__ vT) {
  __shared__ u16 sm[32][33];
  const int t0 = blockIdx.x * 32, d0 = blockIdx.y * 32, b = blockIdx.z;
  const int tx = threadIdx.x & 31, ty = threadIdx.x >> 5;   // ty in [0,8)
#pragma unroll
  for (int i = 0; i < 4; ++i) {
    int t = t0 + i * 8 + ty;
    sm[i * 8 + ty][tx] = qkv[(size_t)(b * 4096 + t) * 3072 + 2048 + d0 + tx];
  }
  __syncthreads();
#pragma unroll
  for (int i = 0; i < 4; ++i) {
    int d = d0 + i * 8 + ty;
    vT[((size_t)b * 1024 + d) * 4096 + t0 + tx] = sm[tx][i * 8 + ty];
  }
}

// ---------- row softmax, in-place on bf16 scores [rows][4096] ----------
__global__ __launch_bounds__(256) void softmax_rows(u16* __restrict__ sc) {
  const size_t row = blockIdx.x;
  u16* p = sc + row * 4096;
  const int tid = threadIdx.x;
  const int wid = tid >> 6, lane = tid & 63;
  bf16x8 c0 = ((const bf16x8*)p)[tid];
  bf16x8 c1 = ((const bf16x8*)p)[tid + 256];
  float v[16];
#pragma unroll
  for (int j = 0; j < 8; ++j) { v[j] = b2f((u16)c0[j]); v[8 + j] = b2f((u16)c1[j]); }
  float mx = v[0];
#pragma unroll
  for (int j = 1; j < 16; ++j) mx = fmaxf(mx, v[j]);
#pragma unroll
  for (int off = 32; off; off >>= 1) mx = fmaxf(mx, __shfl_xor(mx, off));
  __shared__ float redm[4], reds[4];
  if (lane == 0) redm[wid] = mx;
  __syncthreads();
  mx = fmaxf(fmaxf(redm[0], redm[1]), fmaxf(redm[2], redm[3]));
  float s = 0.f;
#pragma unroll
  for (int j = 0; j < 16; ++j) { v[j] = __expf(v[j] - mx); s += v[j]; }
#pragma unroll
  for (int off = 32; off; off >>= 1) s += __shfl_xor(s, off);
  if (lane == 0) reds[wid] = s;
  __syncthreads();
  s = (reds[0] + reds[1]) + (reds[2] + reds[3]);
  float inv = 1.0f / s;
#pragma unroll
  for (int j = 0; j < 8; ++j) {
    c0[j] = (short)f2b(v[j] * inv);
    c1[j] = (short)f2b(v[8 + j] * inv);
  }
  ((bf16x8*)p)[tid] = c0;
  ((bf16x8*)p)[tid + 256] = c1;
}

// ---------- BT GEMM: C[M,N] = scale * (A[M,K] . B[N,K]^T) (+bias[N]) ----------
// m97-style: 128x128 tile, BK=32, 256 threads (4 waves 2x2), 16x16x32 bf16 MFMA
template <int OUT_BF16, int HAS_BIAS>
__global__ __launch_bounds__(256)
void gemm_bt(const u16* __restrict__ A, const u16* __restrict__ B,
             void* __restrict__ Cv, const float* __restrict__ bias,
             int K, int lda, int ldb, int ldc,
             long asb, long bsb, long csb, float scale) {
  __shared__ __align__(16) u16 lA[128 * 32];
  __shared__ __align__(16) u16 lB[128 * 32];
  const int tid = threadIdx.x;
  const int wid = tid >> 6;
  const int lane = tid & 63;
  const int m0 = blockIdx.x * 128;
  const int n0 = blockIdx.y * 128;
  const int z = blockIdx.z;
  A += (size_t)z * asb;
  B += (size_t)z * bsb;

  const int wm = (wid >> 1) * 64;      // wave row offset in tile
  const int wn = (wid & 1) * 64;       // wave col offset in tile
  const int fr = lane & 15;            // fragment row (m or n within 16)
  const int kg = (lane >> 4) * 8;      // k offset within 32

  f32x4 acc[4][4] = {};

  for (int k0 = 0; k0 < K; k0 += 32) {
    // stage 128x32 bf16 tiles (8 KB each) via direct-to-LDS, 16B/lane
#pragma unroll
    for (int i = 0; i < 2; ++i) {
      const int ch = i * 256 + tid;      // 512 chunks of 16B per tile
      const int row = ch >> 2;           // 4 chunks per 64B row
      const int kc = (ch & 3) * 8;       // elem offset in row
      const u16* lds_base_a = lA + (size_t)(i * 256 + wid * 64) * 8;
      const u16* lds_base_b = lB + (size_t)(i * 256 + wid * 64) * 8;
      gload_lds16(A + (size_t)(m0 + row) * lda + (k0 + kc), lds_base_a);
      gload_lds16(B + (size_t)(n0 + row) * ldb + (k0 + kc), lds_base_b);
    }
    __syncthreads();
    bf16x8 aF[4], bF[4];
#pragma unroll
    for (int t = 0; t < 4; ++t) {
      aF[t] = *(const bf16x8*)(lA + (wm + t * 16 + fr) * 32 + kg);
      bF[t] = *(const bf16x8*)(lB + (wn + t * 16 + fr) * 32 + kg);
    }
#pragma unroll
    for (int mi = 0; mi < 4; ++mi)
#pragma unroll
      for (int ni = 0; ni < 4; ++ni)
        acc[mi][ni] = __builtin_amdgcn_mfma_f32_16x16x32_bf16(aF[mi], bF[ni],
                                                              acc[mi][ni], 0, 0, 0);
    __syncthreads();
  }

  // epilogue: C/D layout col = lane&15, row = (lane>>4)*4 + r   [m89-verified]
  const int cl = lane & 15;
  const int rg = (lane >> 4) * 4;
#pragma unroll
  for (int mi = 0; mi < 4; ++mi) {
#pragma unroll
    for (int ni = 0; ni < 4; ++ni) {
      const int gcol = n0 + wn + ni * 16 + cl;
      float bv = HAS_BIAS ? bias[gcol] : 0.0f;
#pragma unroll
      for (int r = 0; r < 4; ++r) {
        const int grow = m0 + wm + mi * 16 + rg + r;
        float v = acc[mi][ni][r] * scale + bv;
        if (OUT_BF16)
          ((u16*)Cv)[(size_t)z * csb + (size_t)grow * ldc + gcol] = f2b(v);
        else
          ((float*)Cv)[(size_t)z * csb + (size_t)grow * ldc + gcol] = v;
      }
    }
  }
}

// ---------- launch ----------
extern "C" void kernel_launch(void* const* d_in, const int* in_sizes, int n_in,
                              void* d_out, int out_size, void* d_ws, size_t ws_size,
                              hipStream_t stream) {
  const float* x    = (const float*)d_in[0];   // [4,4096,1024]
  const float* Wqkv = (const float*)d_in[1];   // [3072,1024]
  const float* bqkv = (const float*)d_in[2];   // [3072]
  const float* Wout = (const float*)d_in[3];   // [1024,1024]
  const float* bout = (const float*)d_in[4];   // [1024]
  float* out = (float*)d_out;                  // [4,4096,1024] fp32

  char* ws = (char*)d_ws;
  const size_t NX   = 16384ull * 1024;      // tokens x dim
  const size_t NQKV = 16384ull * 3072;
  const size_t NSC1 = 4096ull * 4096;       // one batch of scores

  u16* xb    = (u16*)(ws);                                   // 32 MB
  u16* qkvb  = (u16*)(ws + 33554432);                        // 96 MB
  u16* vT    = (u16*)(ws + 134217728);                       // 32 MB
  u16* ctxb  = (u16*)(ws + 167772160);                       // 32 MB
  u16* wqkvb = (u16*)(ws + 201326592);                       // 6 MB
  u16* woutb = (u16*)(ws + 207618048);                       // 2 MB
  u16* sc    = (u16*)(ws + 209715200);                       // 128 MB (or 32 MB)

  const size_t need_batched = 209715200ull + 4 * NSC1 * 2;   // ~344 MB
  const size_t need_serial  = 209715200ull + NSC1 * 2;       // ~232 MB
  if (ws_size < need_serial) return;  // cannot run
  const bool batched = (ws_size >= need_batched);

  // 1) casts
  cast_f32_bf16<<<dim3((int)(NX / 2048)), 256, 0, stream>>>(x, xb, (int)NX);
  cast_f32_bf16<<<dim3(1536), 256, 0, stream>>>(Wqkv, wqkvb, 3072 * 1024);
  cast_f32_bf16<<<dim3(512),  256, 0, stream>>>(Wout, woutb, 1024 * 1024);

  // 2) qkv = x @ Wqkv^T + bqkv   (M=16384,N=3072,K=1024) -> bf16
  gemm_bt<1, 1><<<dim3(128, 24, 1), 256, 0, stream>>>(
      xb, wqkvb, qkvb, bqkv, 1024, 1024, 1024, 3072, 0, 0, 0, 1.0f);

  // 3) vT[b][d][t]
  transpose_v<<<dim3(128, 32, 4), 256, 0, stream>>>(qkvb, vT);

  if (batched) {
    // 4) scores = (q @ k^T)/32 per batch  (M=N=4096,K=1024) -> bf16
    gemm_bt<1, 0><<<dim3(32, 32, 4), 256, 0, stream>>>(
        qkvb, qkvb + 1024, sc, nullptr, 1024, 3072, 3072, 4096,
        4096L * 3072, 4096L * 3072, (long)NSC1, 0.03125f);
    // 5) softmax rows (in-place), all 4 batches
    softmax_rows<<<dim3(16384), 256, 0, stream>>>(sc);
    // 6) ctx = attn @ v  (= attn @ vT^T)  (M=4096,N=1024,K=4096) -> bf16
    gemm_bt<1, 0><<<dim3(32, 8, 4), 256, 0, stream>>>(
        sc, vT, ctxb, nullptr, 4096, 4096, 4096, 1024,
        (long)NSC1, 1024L * 4096, 4096L * 1024, 1.0f);
  } else {
    for (int b = 0; b < 4; ++b) {
      const u16* qb = qkvb + (size_t)b * 4096 * 3072;
      gemm_bt<1, 0><<<dim3(32, 32, 1), 256, 0, stream>>>(
          qb, qb + 1024, sc, nullptr, 1024, 3072, 3072, 4096, 0, 0, 0, 0.03125f);
      softmax_rows<<<dim3(4096), 256, 0, stream>>>(sc);
      gemm_bt<1, 0><<<dim3(32, 8, 1), 256, 0, stream>>>(
          sc, vT + (size_t)b * 1024 * 4096, ctxb + (size_t)b * 4096 * 1024,
          nullptr, 4096, 4096, 4096, 1024, 0, 0, 0, 1.0f);
    }
  }

  // 7) out = ctx @ Wout^T + bout  (M=16384,N=1024,K=1024) -> fp32
  gemm_bt<0, 1><<<dim3(128, 8, 1), 256, 0, stream>>>(
      ctxb, woutb, out, bout, 1024, 1024, 1024, 1024, 0, 0, 0, 1.0f);
}

// Round 2
// 817.922 us; speedup vs baseline: 1.0580x; 1.0580x over previous
//
#include <hip/hip_runtime.h>

typedef unsigned short u16;
typedef unsigned int u32;
typedef __attribute__((ext_vector_type(8))) short bf16x8;
typedef __attribute__((ext_vector_type(4))) float f32x4;

// ---------- helpers ----------
__device__ __forceinline__ u16 f2b(float f) {           // fp32 -> bf16 RNE
  u32 u = __float_as_uint(f);
  u32 r = (u + 0x7fffu + ((u >> 16) & 1u)) >> 16;
  return (u16)r;
}
__device__ __forceinline__ float b2f(u16 b) {
  return __uint_as_float(((u32)b) << 16);
}

typedef const __attribute__((address_space(1))) unsigned int gas_u32;
typedef __attribute__((address_space(3))) unsigned int las_u32;
__device__ __forceinline__ void gload_lds16(const void* g, const void* l) {
  // global -> LDS direct DMA, 16B/lane; LDS dest is wave-uniform base + lane*16
  __builtin_amdgcn_global_load_lds((gas_u32*)(unsigned long long)g,
                                   (las_u32*)(unsigned long long)l, 16, 0, 0);
}

// ---------- cast fp32 -> bf16 ----------
__global__ __launch_bounds__(256) void cast_f32_bf16(const float* __restrict__ in,
                                                     u16* __restrict__ out, int n) {
  int i = (blockIdx.x * 256 + threadIdx.x) * 8;
  if (i >= n) return;
  float4 a = *(const float4*)(in + i);
  float4 b = *(const float4*)(in + i + 4);
  bf16x8 r;
  r[0] = (short)f2b(a.x); r[1] = (short)f2b(a.y);
  r[2] = (short)f2b(a.z); r[3] = (short)f2b(a.w);
  r[4] = (short)f2b(b.x); r[5] = (short)f2b(b.y);
  r[6] = (short)f2b(b.z); r[7] = (short)f2b(b.w);
  *(bf16x8*)(out + i) = r;
}

// ---------- transpose v: qkv[b*4096+t][2048+d] -> vT[b][d][t] ----------
__global__ __launch_bounds__(256) void transpose_v(const u16* __restrict__ qkv,
                                                   u16* __restrict__ vT) {
  __shared__ u16 sm[32][33];
  const int t0 = blockIdx.x * 32, d0 = blockIdx.y * 32, b = blockIdx.z;
  const int tx = threadIdx.x & 31, ty = threadIdx.x >> 5;
#pragma unroll
  for (int i = 0; i < 4; ++i) {
    int t = t0 + i * 8 + ty;
    sm[i * 8 + ty][tx] = qkv[(size_t)(b * 4096 + t) * 3072 + 2048 + d0 + tx];
  }
  __syncthreads();
#pragma unroll
  for (int i = 0; i < 4; ++i) {
    int d = d0 + i * 8 + ty;
    vT[((size_t)b * 1024 + d) * 4096 + t0 + tx] = sm[tx][i * 8 + ty];
  }
}

// ---------- row softmax, in-place bf16 [rows][4096] ----------
__global__ __launch_bounds__(256) void softmax_rows(u16* __restrict__ sc) {
  const size_t row = blockIdx.x;
  u16* p = sc + row * 4096;
  const int tid = threadIdx.x;
  const int wid = tid >> 6, lane = tid & 63;
  bf16x8 c0 = ((const bf16x8*)p)[tid];
  bf16x8 c1 = ((const bf16x8*)p)[tid + 256];
  float v[16];
#pragma unroll
  for (int j = 0; j < 8; ++j) { v[j] = b2f((u16)c0[j]); v[8 + j] = b2f((u16)c1[j]); }
  float mx = v[0];
#pragma unroll
  for (int j = 1; j < 16; ++j) mx = fmaxf(mx, v[j]);
#pragma unroll
  for (int off = 32; off; off >>= 1) mx = fmaxf(mx, __shfl_xor(mx, off));
  __shared__ float redm[4], reds[4];
  if (lane == 0) redm[wid] = mx;
  __syncthreads();
  mx = fmaxf(fmaxf(redm[0], redm[1]), fmaxf(redm[2], redm[3]));
  float s = 0.f;
#pragma unroll
  for (int j = 0; j < 16; ++j) { v[j] = __expf(v[j] - mx); s += v[j]; }
#pragma unroll
  for (int off = 32; off; off >>= 1) s += __shfl_xor(s, off);
  if (lane == 0) reds[wid] = s;
  __syncthreads();
  s = (reds[0] + reds[1]) + (reds[2] + reds[3]);
  float inv = 1.0f / s;
#pragma unroll
  for (int j = 0; j < 8; ++j) {
    c0[j] = (short)f2b(v[j] * inv);
    c1[j] = (short)f2b(v[8 + j] * inv);
  }
  ((bf16x8*)p)[tid] = c0;
  ((bf16x8*)p)[tid + 256] = c1;
}

// ============ 256x256 8-phase BT GEMM (m201-style, T1+T2+T3+T4+T5) ============
// C[M,N] = scale*(A[M,K] . B[N,K]^T) (+bias[N]); 512 thr = 8 waves (2Mx4N),
// per-wave 128x64 out; BK=64; LDS 128 KiB dbuf; st_16x32 swizzle both sides;
// counted vmcnt(8) (never 0 mid-loop); setprio around MFMA clusters.
template <int OUT_BF16, int HAS_BIAS>
__global__ __launch_bounds__(512, 2)
void gemm256(const u16* __restrict__ A, const u16* __restrict__ B,
             void* __restrict__ Cv, const float* __restrict__ bias,
             int K, int lda, int ldb, int ldc,
             long asb, long bsb, long csb, float scale, int gx) {
  __shared__ __align__(16) u16 lds[65536];  // [A0|B0|A1|B1] x 32KB each
  const int tid = threadIdx.x;
  const int wid = tid >> 6, lane = tid & 63;
  const int wr = wid >> 2, wc = wid & 3;
  const int z = blockIdx.y;
  // XCD-aware bijective swizzle (gridDim.x % 8 == 0 for all our launches)
  const int nwg = gridDim.x;
  const int orig = blockIdx.x;
  const int swzb = (orig & 7) * (nwg >> 3) + (orig >> 3);
  const int m0 = (swzb % gx) * 256;
  const int n0 = (swzb / gx) * 256;
  A += (size_t)z * asb;
  B += (size_t)z * bsb;

  // --- per-lane stage source coords: phys chunk -> linear (inverse st_16x32) ---
  // LDS elem layout: subtile st = (rowBlk*2 + colBlk), off = st*512 + r16*32 + c32
  const u16* sA[4];
  const u16* sB[4];
#pragma unroll
  for (int j = 0; j < 4; ++j) {
    int p = j * 8192 + wid * 1024 + lane * 16;          // phys byte offset
    int linb = p ^ (((p >> 9) & 1) << 5);               // involution
    int e = linb >> 1;                                   // elem index
    int row = ((e >> 10) << 4) | ((e >> 5) & 15);        // (st>>1)*16 + r16
    int col = (((e >> 9) & 1) << 5) | (e & 31);          // (st&1)*32 + c32
    sA[j] = A + (size_t)(m0 + row) * lda + col;
    sB[j] = B + (size_t)(n0 + row) * ldb + col;
  }

  // --- swizzled ds_read fragment address pieces ---
  const int fr = lane & 15;                 // frag row within 16-block
  const int kq2 = ((lane >> 4) & 3) * 16;   // k-group byte offset (8 elems)
  const int swz = ((lane >> 3) & 1) << 5;   // ((fr>>3)&1)<<5 byte XOR

#define FRAG(base, blk)                                                     \
  (*(const bf16x8*)((const char*)(base) + ((((blk)*1024 + fr*64 + kq2)) ^ swz)))

#define STAGE(dA, dB, k0)                                                   \
  {                                                                         \
    _Pragma("unroll") for (int j = 0; j < 4; ++j) {                         \
      gload_lds16(sA[j] + (k0), (dA) + j * 4096 + wid * 512);               \
      gload_lds16(sB[j] + (k0), (dB) + j * 4096 + wid * 512);               \
    }                                                                       \
  }

  f32x4 acc[8][4] = {};
  const int NT = K >> 6;

  // prologue: stage tiles 0 and 1
  STAGE(lds, lds + 16384, 0);
  STAGE(lds + 32768, lds + 49152, 64);
  asm volatile("s_waitcnt vmcnt(8)" ::: "memory");   // tile0's 8 done
  asm volatile("s_barrier" ::: "memory");

  int cur = 0;
  for (int t = 0; t < NT; ++t) {
    u16* lA = lds + cur * 32768;
    u16* lB = lA + 16384;
    bf16x8 aF[8], bF[8];
    // ---- P1: read A(mh0) + B(nh0); MFMA quadrant (mh0,nh0) ----
#pragma unroll
    for (int m = 0; m < 4; ++m)
#pragma unroll
      for (int kh = 0; kh < 2; ++kh)
        aF[m * 2 + kh] = FRAG(lA, (wr * 8 + m) * 2 + kh);
#pragma unroll
    for (int n = 0; n < 2; ++n)
#pragma unroll
      for (int kh = 0; kh < 2; ++kh)
        bF[n * 2 + kh] = FRAG(lB, (wc * 4 + n) * 2 + kh);
    __builtin_amdgcn_s_setprio(1);
#pragma unroll
    for (int m = 0; m < 4; ++m)
#pragma unroll
      for (int n = 0; n < 2; ++n)
#pragma unroll
        for (int kh = 0; kh < 2; ++kh)
          acc[m][n] = __builtin_amdgcn_mfma_f32_16x16x32_bf16(
              aF[m * 2 + kh], bF[n * 2 + kh], acc[m][n], 0, 0, 0);
    __builtin_amdgcn_s_setprio(0);
    // ---- P2: read B(nh1); MFMA (mh0,nh1) ----
#pragma unroll
    for (int n = 2; n < 4; ++n)
#pragma unroll
      for (int kh = 0; kh < 2; ++kh)
        bF[n * 2 + kh] = FRAG(lB, (wc * 4 + n) * 2 + kh);
    __builtin_amdgcn_s_setprio(1);
#pragma unroll
    for (int m = 0; m < 4; ++m)
#pragma unroll
      for (int n = 2; n < 4; ++n)
#pragma unroll
        for (int kh = 0; kh < 2; ++kh)
          acc[m][n] = __builtin_amdgcn_mfma_f32_16x16x32_bf16(
              aF[m * 2 + kh], bF[n * 2 + kh], acc[m][n], 0, 0, 0);
    __builtin_amdgcn_s_setprio(0);
    // ---- P3: read A(mh1); MFMA (mh1,nh0) ----
#pragma unroll
    for (int m = 0; m < 4; ++m)
#pragma unroll
      for (int kh = 0; kh < 2; ++kh)
        aF[m * 2 + kh] = FRAG(lA, (wr * 8 + 4 + m) * 2 + kh);
    __builtin_amdgcn_s_setprio(1);
#pragma unroll
    for (int m = 0; m < 4; ++m)
#pragma unroll
      for (int n = 0; n < 2; ++n)
#pragma unroll
        for (int kh = 0; kh < 2; ++kh)
          acc[4 + m][n] = __builtin_amdgcn_mfma_f32_16x16x32_bf16(
              aF[m * 2 + kh], bF[n * 2 + kh], acc[4 + m][n], 0, 0, 0);
    __builtin_amdgcn_s_setprio(0);
    // ---- all reads of buf[cur] done: WAR barrier, then restage with t+2 ----
    if (t + 2 < NT) {
      asm volatile("s_waitcnt lgkmcnt(0)" ::: "memory");
      asm volatile("s_barrier" ::: "memory");
      STAGE(lA, lB, (t + 2) << 6);
    }
    // ---- P4: MFMA (mh1,nh1) (regs already loaded) ----
    __builtin_amdgcn_s_setprio(1);
#pragma unroll
    for (int m = 0; m < 4; ++m)
#pragma unroll
      for (int n = 2; n < 4; ++n)
#pragma unroll
        for (int kh = 0; kh < 2; ++kh)
          acc[4 + m][n] = __builtin_amdgcn_mfma_f32_16x16x32_bf16(
              aF[m * 2 + kh], bF[n * 2 + kh], acc[4 + m][n], 0, 0, 0);
    __builtin_amdgcn_s_setprio(0);
    // ---- RAW: my tile-(t+1) loads done (t+2's 8 stay in flight) ----
    if (t + 1 < NT) {
      if (t + 2 < NT) {
        asm volatile("s_waitcnt vmcnt(8)" ::: "memory");
      } else {
        asm volatile("s_waitcnt vmcnt(0)" ::: "memory");
      }
      asm volatile("s_barrier" ::: "memory");
    }
    cur ^= 1;
  }

  // ---- epilogue: C/D layout col=lane&15, row=(lane>>4)*4+r ----
  const int cl = lane & 15, rg4 = (lane >> 4) * 4;
#pragma unroll
  for (int m = 0; m < 8; ++m) {
#pragma unroll
    for (int n = 0; n < 4; ++n) {
      const int gcol = n0 + wc * 64 + n * 16 + cl;
      const float bv = HAS_BIAS ? bias[gcol] : 0.0f;
#pragma unroll
      for (int r = 0; r < 4; ++r) {
        const int grow = m0 + wr * 128 + m * 16 + rg4 + r;
        const float v = acc[m][n][r] * scale + bv;
        if (OUT_BF16)
          ((u16*)Cv)[(size_t)z * csb + (size_t)grow * ldc + gcol] = f2b(v);
        else
          ((float*)Cv)[(size_t)z * csb + (size_t)grow * ldc + gcol] = v;
      }
    }
  }
#undef FRAG
#undef STAGE
}

// ---------- launch ----------
extern "C" void kernel_launch(void* const* d_in, const int* in_sizes, int n_in,
                              void* d_out, int out_size, void* d_ws, size_t ws_size,
                              hipStream_t stream) {
  const float* x    = (const float*)d_in[0];
  const float* Wqkv = (const float*)d_in[1];
  const float* bqkv = (const float*)d_in[2];
  const float* Wout = (const float*)d_in[3];
  const float* bout = (const float*)d_in[4];
  float* out = (float*)d_out;

  char* ws = (char*)d_ws;
  const size_t NX   = 16384ull * 1024;
  const size_t NSC1 = 4096ull * 4096;

  u16* xb    = (u16*)(ws);
  u16* qkvb  = (u16*)(ws + 33554432);
  u16* vT    = (u16*)(ws + 134217728);
  u16* ctxb  = (u16*)(ws + 167772160);
  u16* wqkvb = (u16*)(ws + 201326592);
  u16* woutb = (u16*)(ws + 207618048);
  u16* sc    = (u16*)(ws + 209715200);

  const size_t need_batched = 209715200ull + 4 * NSC1 * 2;
  const size_t need_serial  = 209715200ull + NSC1 * 2;
  if (ws_size < need_serial) return;
  const bool batched = (ws_size >= need_batched);

  cast_f32_bf16<<<dim3((int)(NX / 2048)), 256, 0, stream>>>(x, xb, (int)NX);
  cast_f32_bf16<<<dim3(1536), 256, 0, stream>>>(Wqkv, wqkvb, 3072 * 1024);
  cast_f32_bf16<<<dim3(512),  256, 0, stream>>>(Wout, woutb, 1024 * 1024);

  // qkv = x @ Wqkv^T + bqkv : M=16384 N=3072 K=1024, grid 64x12=768
  gemm256<1, 1><<<dim3(768, 1), 512, 0, stream>>>(
      xb, wqkvb, qkvb, bqkv, 1024, 1024, 1024, 3072, 0, 0, 0, 1.0f, 64);

  transpose_v<<<dim3(128, 32, 4), 256, 0, stream>>>(qkvb, vT);

  if (batched) {
    // scores = (q @ k^T)/32 : M=N=4096 K=1024 per batch, grid 16x16=256 x4
    gemm256<1, 0><<<dim3(256, 4), 512, 0, stream>>>(
        qkvb, qkvb + 1024, sc, nullptr, 1024, 3072, 3072, 4096,
        4096L * 3072, 4096L * 3072, (long)NSC1, 0.03125f, 16);
    softmax_rows<<<dim3(16384), 256, 0, stream>>>(sc);
    // ctx = attn @ vT^T : M=4096 N=1024 K=4096, grid 16x4=64 x4
    gemm256<1, 0><<<dim3(64, 4), 512, 0, stream>>>(
        sc, vT, ctxb, nullptr, 4096, 4096, 4096, 1024,
        (long)NSC1, 1024L * 4096, 4096L * 1024, 1.0f, 16);
  } else {
    for (int b = 0; b < 4; ++b) {
      const u16* qb = qkvb + (size_t)b * 4096 * 3072;
      gemm256<1, 0><<<dim3(256, 1), 512, 0, stream>>>(
          qb, qb + 1024, sc, nullptr, 1024, 3072, 3072, 4096, 0, 0, 0,
          0.03125f, 16);
      softmax_rows<<<dim3(4096), 256, 0, stream>>>(sc);
      gemm256<1, 0><<<dim3(64, 1), 512, 0, stream>>>(
          sc, vT + (size_t)b * 1024 * 4096, ctxb + (size_t)b * 4096 * 1024,
          nullptr, 4096, 4096, 4096, 1024, 0, 0, 0, 1.0f, 16);
    }
  }

  // out = ctx @ Wout^T + bout : M=16384 N=1024 K=1024, grid 64x4=256
  gemm256<0, 1><<<dim3(256, 1), 512, 0, stream>>>(
      ctxb, woutb, out, bout, 1024, 1024, 1024, 1024, 0, 0, 0, 1.0f, 64);
}

// Round 3
// 558.312 us; speedup vs baseline: 1.5499x; 1.4650x over previous
//
#include <hip/hip_runtime.h>

typedef unsigned short u16;
typedef unsigned int u32;
typedef __attribute__((ext_vector_type(8))) short bf16x8;
typedef __attribute__((ext_vector_type(4))) float f32x4;

// ---------- helpers ----------
__device__ __forceinline__ u16 f2b(float f) {           // fp32 -> bf16 RNE
  u32 u = __float_as_uint(f);
  u32 r = (u + 0x7fffu + ((u >> 16) & 1u)) >> 16;
  return (u16)r;
}
__device__ __forceinline__ float b2f(u16 b) {
  return __uint_as_float(((u32)b) << 16);
}

typedef const __attribute__((address_space(1))) unsigned int gas_u32;
typedef __attribute__((address_space(3))) unsigned int las_u32;
__device__ __forceinline__ void gload_lds16(const void* g, const void* l) {
  // global -> LDS direct DMA, 16B/lane; LDS dest is wave-uniform base + lane*16
  __builtin_amdgcn_global_load_lds((gas_u32*)(unsigned long long)g,
                                   (las_u32*)(unsigned long long)l, 16, 0, 0);
}

// ---------- cast fp32 -> bf16 ----------
__global__ __launch_bounds__(256) void cast_f32_bf16(const float* __restrict__ in,
                                                     u16* __restrict__ out, int n) {
  int i = (blockIdx.x * 256 + threadIdx.x) * 8;
  if (i >= n) return;
  float4 a = *(const float4*)(in + i);
  float4 b = *(const float4*)(in + i + 4);
  bf16x8 r;
  r[0] = (short)f2b(a.x); r[1] = (short)f2b(a.y);
  r[2] = (short)f2b(a.z); r[3] = (short)f2b(a.w);
  r[4] = (short)f2b(b.x); r[5] = (short)f2b(b.y);
  r[6] = (short)f2b(b.z); r[7] = (short)f2b(b.w);
  *(bf16x8*)(out + i) = r;
}

// ---------- transpose v: qkv[b*4096+t][2048+d] -> vT[b][d][t] ----------
__global__ __launch_bounds__(256) void transpose_v(const u16* __restrict__ qkv,
                                                   u16* __restrict__ vT) {
  __shared__ u16 sm[32][33];
  const int t0 = blockIdx.x * 32, d0 = blockIdx.y * 32, b = blockIdx.z;
  const int tx = threadIdx.x & 31, ty = threadIdx.x >> 5;
#pragma unroll
  for (int i = 0; i < 4; ++i) {
    int t = t0 + i * 8 + ty;
    sm[i * 8 + ty][tx] = qkv[(size_t)(b * 4096 + t) * 3072 + 2048 + d0 + tx];
  }
  __syncthreads();
#pragma unroll
  for (int i = 0; i < 4; ++i) {
    int d = d0 + i * 8 + ty;
    vT[((size_t)b * 1024 + d) * 4096 + t0 + tx] = sm[tx][i * 8 + ty];
  }
}

// ---------- row softmax, in-place bf16 [rows][4096] ----------
__global__ __launch_bounds__(256) void softmax_rows(u16* __restrict__ sc) {
  const size_t row = blockIdx.x;
  u16* p = sc + row * 4096;
  const int tid = threadIdx.x;
  const int wid = tid >> 6, lane = tid & 63;
  bf16x8 c0 = ((const bf16x8*)p)[tid];
  bf16x8 c1 = ((const bf16x8*)p)[tid + 256];
  float v[16];
#pragma unroll
  for (int j = 0; j < 8; ++j) { v[j] = b2f((u16)c0[j]); v[8 + j] = b2f((u16)c1[j]); }
  float mx = v[0];
#pragma unroll
  for (int j = 1; j < 16; ++j) mx = fmaxf(mx, v[j]);
#pragma unroll
  for (int off = 32; off; off >>= 1) mx = fmaxf(mx, __shfl_xor(mx, off));
  __shared__ float redm[4], reds[4];
  if (lane == 0) redm[wid] = mx;
  __syncthreads();
  mx = fmaxf(fmaxf(redm[0], redm[1]), fmaxf(redm[2], redm[3]));
  float s = 0.f;
#pragma unroll
  for (int j = 0; j < 16; ++j) { v[j] = __expf(v[j] - mx); s += v[j]; }
#pragma unroll
  for (int off = 32; off; off >>= 1) s += __shfl_xor(s, off);
  if (lane == 0) reds[wid] = s;
  __syncthreads();
  s = (reds[0] + reds[1]) + (reds[2] + reds[3]);
  float inv = 1.0f / s;
#pragma unroll
  for (int j = 0; j < 8; ++j) {
    c0[j] = (short)f2b(v[j] * inv);
    c1[j] = (short)f2b(v[8 + j] * inv);
  }
  ((bf16x8*)p)[tid] = c0;
  ((bf16x8*)p)[tid + 256] = c1;
}

// ======== 256x256 ring-4 pipelined BT GEMM ========
// C[M,N] = scale*(A[M,K] . B[N,K]^T) (+bias[N]); 512 thr = 8 waves (2Mx4N),
// per-wave 128x64 out. BK=32; LDS = 4-deep ring of (A 16KB | B 16KB) = 128KB.
// Stage tile t+3 while computing tile t -> ONE barrier + one counted vmcnt per
// K-step; vmcnt never drains to 0 mid-loop (T4). Swizzle: byte ^= (row&3)<<4,
// applied on BOTH pre-swizzled gload source and ds_read addr (rule #21).
// WAR safety: buf[(t+3)&3]=buf[(t-1)&3]; every wave's ds_reads of tile t-1
// completed before it issued its step-(t-1) MFMAs (compiler lgkmcnt), which
// precede its step-t barrier => stage-after-barrier cannot race the reads.
template <int OUT_BF16, int HAS_BIAS>
__global__ __launch_bounds__(512, 2)
void gemm256(const u16* __restrict__ A, const u16* __restrict__ B,
             void* __restrict__ Cv, const float* __restrict__ bias,
             int K, int lda, int ldb, int ldc,
             long asb, long bsb, long csb, float scale, int gx) {
  __shared__ __align__(16) u16 lds[65536];  // 4 x (A 8192 u16 | B 8192 u16)
  const int tid = threadIdx.x;
  const int wid = tid >> 6, lane = tid & 63;
  const int wr = wid >> 2, wc = wid & 3;
  const int z = blockIdx.y;
  const int nwg = gridDim.x;          // always % 8 == 0 here
  const int orig = blockIdx.x;
  const int swzb = (orig & 7) * (nwg >> 3) + (orig >> 3);  // XCD swizzle (T1)
  const int m0 = (swzb % gx) * 256;
  const int n0 = (swzb / gx) * 256;
  A += (size_t)z * asb;
  B += (size_t)z * bsb;

  // per-lane stage source (tile k0=0): phys byte p -> (row, colElem) via
  // inverse swizzle (involution on the 16B-chunk bits)
  const u16* sA[2];
  const u16* sB[2];
#pragma unroll
  for (int j = 0; j < 2; ++j) {
    int p = j * 8192 + wid * 1024 + lane * 16;   // byte offset in 16KB tile
    int row = p >> 6;                             // 64B per row (32 elems)
    int chl = ((p >> 4) & 3) ^ (row & 3);         // linear 16B chunk
    int colE = chl * 8 + ((p & 15) >> 1);
    sA[j] = A + (size_t)(m0 + row) * lda + colE;
    sB[j] = B + (size_t)(n0 + row) * ldb + colE;
  }
  const int NT = K >> 5;

#define STAGE(tt)                                                          \
  {                                                                        \
    u16* bb = lds + ((tt) & 3) * 16384;                                    \
    _Pragma("unroll") for (int j = 0; j < 2; ++j) {                        \
      gload_lds16(sA[j] + ((tt) << 5), bb + j * 4096 + wid * 512);         \
      gload_lds16(sB[j] + ((tt) << 5), bb + 8192 + j * 4096 + wid * 512);  \
    }                                                                      \
  }

  const int fr = lane & 15;
  const int kq16 = (lane >> 4) * 16;   // byte offset of lane's 8-elem k-group

  f32x4 acc[8][4] = {};

  STAGE(0);
  if (NT > 1) STAGE(1);
  if (NT > 2) STAGE(2);

  for (int t = 0; t < NT; ++t) {
    // RAW: tile t's 4 gloads retired (FIFO); keep t+1,t+2 (8) in flight
    if (t + 2 < NT)      asm volatile("s_waitcnt vmcnt(8)" ::: "memory");
    else if (t + 1 < NT) asm volatile("s_waitcnt vmcnt(4)" ::: "memory");
    else                 asm volatile("s_waitcnt vmcnt(0)" ::: "memory");
    asm volatile("s_barrier" ::: "memory");

    const char* bufA = (const char*)(lds + (t & 3) * 16384);
    const char* bufB = bufA + 16384;  // B at +16KB bytes
    bf16x8 aF[8], bF[4];
#pragma unroll
    for (int m = 0; m < 8; ++m) {
      const int row = wr * 128 + m * 16 + fr;
      aF[m] = *(const bf16x8*)(bufA + row * 64 + (kq16 ^ ((row & 3) << 4)));
    }
#pragma unroll
    for (int n = 0; n < 4; ++n) {
      const int row = wc * 64 + n * 16 + fr;
      bF[n] = *(const bf16x8*)(bufB + row * 64 + (kq16 ^ ((row & 3) << 4)));
    }
    if (t + 3 < NT) STAGE(t + 3);   // writes buf freed by this step's barrier
    __builtin_amdgcn_s_setprio(1);
#pragma unroll
    for (int m = 0; m < 8; ++m)
#pragma unroll
      for (int n = 0; n < 4; ++n)
        acc[m][n] = __builtin_amdgcn_mfma_f32_16x16x32_bf16(aF[m], bF[n],
                                                            acc[m][n], 0, 0, 0);
    __builtin_amdgcn_s_setprio(0);
  }

  // epilogue: C/D layout col=lane&15, row=(lane>>4)*4+r  [m89-verified]
  const int cl = lane & 15, rg4 = (lane >> 4) * 4;
#pragma unroll
  for (int m = 0; m < 8; ++m) {
#pragma unroll
    for (int n = 0; n < 4; ++n) {
      const int gcol = n0 + wc * 64 + n * 16 + cl;
      const float bv = HAS_BIAS ? bias[gcol] : 0.0f;
#pragma unroll
      for (int r = 0; r < 4; ++r) {
        const int grow = m0 + wr * 128 + m * 16 + rg4 + r;
        const float v = acc[m][n][r] * scale + bv;
        if (OUT_BF16)
          ((u16*)Cv)[(size_t)z * csb + (size_t)grow * ldc + gcol] = f2b(v);
        else
          ((float*)Cv)[(size_t)z * csb + (size_t)grow * ldc + gcol] = v;
      }
    }
  }
#undef STAGE
}

// ---------- launch ----------
extern "C" void kernel_launch(void* const* d_in, const int* in_sizes, int n_in,
                              void* d_out, int out_size, void* d_ws, size_t ws_size,
                              hipStream_t stream) {
  const float* x    = (const float*)d_in[0];
  const float* Wqkv = (const float*)d_in[1];
  const float* bqkv = (const float*)d_in[2];
  const float* Wout = (const float*)d_in[3];
  const float* bout = (const float*)d_in[4];
  float* out = (float*)d_out;

  char* ws = (char*)d_ws;
  const size_t NX = 16384ull * 1024;
  const size_t FIXED = 176160768ull;  // qkv 96MB + vT 32 + ctx 32 + w 8

  // attention chunk size c (batches per scores buffer); sc shares region w/ xb
  int c;
  if      (ws_size >= 134217728ull + FIXED) c = 4;   // 296 MB
  else if (ws_size >=  67108864ull + FIXED) c = 2;   // 232 MB
  else if (ws_size >=  33554432ull + FIXED) c = 1;   // 200 MB
  else return;
  const size_t S0 = (size_t)c * 33554432ull;

  u16* xb    = (u16*)(ws);                       // dead before sc is written
  u16* sc    = (u16*)(ws);
  u16* qkvb  = (u16*)(ws + S0);
  u16* vT    = (u16*)(ws + S0 + 100663296ull);
  u16* ctxb  = (u16*)(ws + S0 + 134217728ull);
  u16* wqkvb = (u16*)(ws + S0 + 167772160ull);
  u16* woutb = (u16*)(ws + S0 + 174063616ull);

  cast_f32_bf16<<<dim3((int)(NX / 2048)), 256, 0, stream>>>(x, xb, (int)NX);
  cast_f32_bf16<<<dim3(1536), 256, 0, stream>>>(Wqkv, wqkvb, 3072 * 1024);
  cast_f32_bf16<<<dim3(512),  256, 0, stream>>>(Wout, woutb, 1024 * 1024);

  // qkv = x @ Wqkv^T + bqkv : M=16384 N=3072 K=1024, grid 64x12=768
  gemm256<1, 1><<<dim3(768, 1), 512, 0, stream>>>(
      xb, wqkvb, qkvb, bqkv, 1024, 1024, 1024, 3072, 0, 0, 0, 1.0f, 64);

  transpose_v<<<dim3(128, 32, 4), 256, 0, stream>>>(qkvb, vT);

  for (int b0 = 0; b0 < 4; b0 += c) {
    const u16* qb = qkvb + (size_t)b0 * 4096 * 3072;
    // scores = (q @ k^T)/32 : M=N=4096 K=1024, grid 256 x c
    gemm256<1, 0><<<dim3(256, c), 512, 0, stream>>>(
        qb, qb + 1024, sc, nullptr, 1024, 3072, 3072, 4096,
        4096L * 3072, 4096L * 3072, 4096L * 4096, 0.03125f, 16);
    softmax_rows<<<dim3(4096 * c), 256, 0, stream>>>(sc);
    // ctx = attn @ vT^T : M=4096 N=1024 K=4096, grid 64 x c
    gemm256<1, 0><<<dim3(64, c), 512, 0, stream>>>(
        sc, vT + (size_t)b0 * 1024 * 4096, ctxb + (size_t)b0 * 4096 * 1024,
        nullptr, 4096, 4096, 4096, 1024,
        4096L * 4096, 1024L * 4096, 4096L * 1024, 1.0f, 16);
  }

  // out = ctx @ Wout^T + bout : M=16384 N=1024 K=1024, grid 64x4=256
  gemm256<0, 1><<<dim3(256, 1), 512, 0, stream>>>(
      ctxb, woutb, out, bout, 1024, 1024, 1024, 1024, 0, 0, 0, 1.0f, 64);
}

// Round 4
// 540.183 us; speedup vs baseline: 1.6019x; 1.0336x over previous
//
#include <hip/hip_runtime.h>

typedef unsigned short u16;
typedef unsigned int u32;
typedef __attribute__((ext_vector_type(8))) short bf16x8;
typedef __attribute__((ext_vector_type(4))) float f32x4;

// ---------- helpers ----------
__device__ __forceinline__ u16 f2b(float f) {           // fp32 -> bf16 RNE
  u32 u = __float_as_uint(f);
  u32 r = (u + 0x7fffu + ((u >> 16) & 1u)) >> 16;
  return (u16)r;
}
__device__ __forceinline__ float b2f(u16 b) {
  return __uint_as_float(((u32)b) << 16);
}

typedef const __attribute__((address_space(1))) unsigned int gas_u32;
typedef __attribute__((address_space(3))) unsigned int las_u32;
__device__ __forceinline__ void gload_lds16(const void* g, const void* l) {
  __builtin_amdgcn_global_load_lds((gas_u32*)(unsigned long long)g,
                                   (las_u32*)(unsigned long long)l, 16, 0, 0);
}

// ---------- cast fp32 -> bf16 ----------
__global__ __launch_bounds__(256) void cast_f32_bf16(const float* __restrict__ in,
                                                     u16* __restrict__ out, int n) {
  int i = (blockIdx.x * 256 + threadIdx.x) * 8;
  if (i >= n) return;
  float4 a = *(const float4*)(in + i);
  float4 b = *(const float4*)(in + i + 4);
  bf16x8 r;
  r[0] = (short)f2b(a.x); r[1] = (short)f2b(a.y);
  r[2] = (short)f2b(a.z); r[3] = (short)f2b(a.w);
  r[4] = (short)f2b(b.x); r[5] = (short)f2b(b.y);
  r[6] = (short)f2b(b.z); r[7] = (short)f2b(b.w);
  *(bf16x8*)(out + i) = r;
}

// ---------- transpose v: qkv[b*4096+t][2048+d] -> vT[b][d][t] ----------
__global__ __launch_bounds__(256) void transpose_v(const u16* __restrict__ qkv,
                                                   u16* __restrict__ vT) {
  __shared__ u16 sm[32][33];
  const int t0 = blockIdx.x * 32, d0 = blockIdx.y * 32, b = blockIdx.z;
  const int tx = threadIdx.x & 31, ty = threadIdx.x >> 5;
#pragma unroll
  for (int i = 0; i < 4; ++i) {
    int t = t0 + i * 8 + ty;
    sm[i * 8 + ty][tx] = qkv[(size_t)(b * 4096 + t) * 3072 + 2048 + d0 + tx];
  }
  __syncthreads();
#pragma unroll
  for (int i = 0; i < 4; ++i) {
    int d = d0 + i * 8 + ty;
    vT[((size_t)b * 1024 + d) * 4096 + t0 + tx] = sm[tx][i * 8 + ty];
  }
}

// ---------- row softmax, in-place bf16 [rows][4096] ----------
__global__ __launch_bounds__(256) void softmax_rows(u16* __restrict__ sc) {
  const size_t row = blockIdx.x;
  u16* p = sc + row * 4096;
  const int tid = threadIdx.x;
  const int wid = tid >> 6, lane = tid & 63;
  bf16x8 c0 = ((const bf16x8*)p)[tid];
  bf16x8 c1 = ((const bf16x8*)p)[tid + 256];
  float v[16];
#pragma unroll
  for (int j = 0; j < 8; ++j) { v[j] = b2f((u16)c0[j]); v[8 + j] = b2f((u16)c1[j]); }
  float mx = v[0];
#pragma unroll
  for (int j = 1; j < 16; ++j) mx = fmaxf(mx, v[j]);
#pragma unroll
  for (int off = 32; off; off >>= 1) mx = fmaxf(mx, __shfl_xor(mx, off));
  __shared__ float redm[4], reds[4];
  if (lane == 0) redm[wid] = mx;
  __syncthreads();
  mx = fmaxf(fmaxf(redm[0], redm[1]), fmaxf(redm[2], redm[3]));
  float s = 0.f;
#pragma unroll
  for (int j = 0; j < 16; ++j) { v[j] = __expf(v[j] - mx); s += v[j]; }
#pragma unroll
  for (int off = 32; off; off >>= 1) s += __shfl_xor(s, off);
  if (lane == 0) reds[wid] = s;
  __syncthreads();
  s = (reds[0] + reds[1]) + (reds[2] + reds[3]);
  float inv = 1.0f / s;
#pragma unroll
  for (int j = 0; j < 8; ++j) {
    c0[j] = (short)f2b(v[j] * inv);
    c1[j] = (short)f2b(v[8 + j] * inv);
  }
  ((bf16x8*)p)[tid] = c0;
  ((bf16x8*)p)[tid + 256] = c1;
}

// ======== 256x256 ring-4 pipelined BT GEMM, st_16x32 LDS swizzle ========
// C[M,N] = scale*(A[M,K] . B[N,K]^T) (+bias[N]); 512 thr = 8 waves (2Mx4N),
// per-wave 128x64 out. BK=32; LDS = 4-deep ring of (A 16KB | B 16KB) = 128KB.
// Stage tile t+3 while computing tile t: ONE barrier + one counted vmcnt per
// K-step; vmcnt never drains to 0 mid-loop (T4).
// LDS layout (per 16KB tile): subtile s = row>>4 (1024B each), within:
// byte = s*1024 + (row&15)*64 + col*2, then XOR ((byte>>9)&1)<<5  [st_16x32,
// 0 conflicts verified in round 2 / m201]. Same involution on gload source
// decode and ds_read address (rule #21).
// XCD swizzle (T1): same-XCD chunks are m-major (n fastest) so each XCD's L2
// holds an A-slice; cuts A re-fetch ~8x.
template <int OUT_BF16, int HAS_BIAS>
__global__ __launch_bounds__(512, 2)
void gemm256(const u16* __restrict__ A, const u16* __restrict__ B,
             void* __restrict__ Cv, const float* __restrict__ bias,
             int K, int lda, int ldb, int ldc,
             long asb, long bsb, long csb, float scale, int gy) {
  __shared__ __align__(16) u16 lds[65536];  // 4 x (A 8192 u16 | B 8192 u16)
  const int tid = threadIdx.x;
  const int wid = tid >> 6, lane = tid & 63;
  const int wr = wid >> 2, wc = wid & 3;
  const int z = blockIdx.y;
  const int nwg = gridDim.x;          // always % 8 == 0 here
  const int orig = blockIdx.x;
  const int swzb = (orig & 7) * (nwg >> 3) + (orig >> 3);  // XCD chunk (T1)
  const int m0 = (swzb / gy) * 256;   // m-major within XCD chunk
  const int n0 = (swzb % gy) * 256;
  A += (size_t)z * asb;
  B += (size_t)z * bsb;

  // per-lane stage source: phys byte p -> linear (involution) -> (row,col)
  const u16* sA[2];
  const u16* sB[2];
#pragma unroll
  for (int j = 0; j < 2; ++j) {
    int p = j * 8192 + wid * 1024 + lane * 16;   // byte offset in 16KB tile
    int lin = p ^ (((p >> 9) & 1) << 5);
    int row = ((lin >> 10) << 4) | ((lin >> 6) & 15);
    int colE = (lin & 63) >> 1;
    sA[j] = A + (size_t)(m0 + row) * lda + colE;
    sB[j] = B + (size_t)(n0 + row) * ldb + colE;
  }
  const int NT = K >> 5;

#define STAGE(tt)                                                          \
  {                                                                        \
    u16* bb = lds + ((tt) & 3) * 16384;                                    \
    _Pragma("unroll") for (int j = 0; j < 2; ++j) {                        \
      gload_lds16(sA[j] + ((tt) << 5), bb + j * 4096 + wid * 512);         \
      gload_lds16(sB[j] + ((tt) << 5), bb + 8192 + j * 4096 + wid * 512);  \
    }                                                                      \
  }

  const int fr = lane & 15;
  const int kq16 = (lane >> 4) * 16;        // 16B k-group within 64B row
  const int swz = (fr & 8) << 2;            // st_16x32 XOR (bit5 from fr bit3)

  f32x4 acc[8][4] = {};

  STAGE(0);
  if (NT > 1) STAGE(1);
  if (NT > 2) STAGE(2);

  for (int t = 0; t < NT; ++t) {
    // RAW: tile t's 4 gloads retired (FIFO); keep t+1,t+2 (8) in flight
    if (t + 2 < NT)      asm volatile("s_waitcnt vmcnt(8)" ::: "memory");
    else if (t + 1 < NT) asm volatile("s_waitcnt vmcnt(4)" ::: "memory");
    else                 asm volatile("s_waitcnt vmcnt(0)" ::: "memory");
    asm volatile("s_barrier" ::: "memory");

    const char* bufA = (const char*)(lds + (t & 3) * 16384);
    const char* bufB = bufA + 16384;
    bf16x8 aF[8], bF[4];
#pragma unroll
    for (int m = 0; m < 8; ++m) {
      const int s = wr * 8 + m;             // subtile = 16-row block
      aF[m] = *(const bf16x8*)(bufA + s * 1024 + fr * 64 + (kq16 ^ swz));
    }
#pragma unroll
    for (int n = 0; n < 4; ++n) {
      const int s = wc * 4 + n;
      bF[n] = *(const bf16x8*)(bufB + s * 1024 + fr * 64 + (kq16 ^ swz));
    }
    if (t + 3 < NT) STAGE(t + 3);   // writes buf freed by this step's barrier
    __builtin_amdgcn_s_setprio(1);
#pragma unroll
    for (int m = 0; m < 8; ++m)
#pragma unroll
      for (int n = 0; n < 4; ++n)
        acc[m][n] = __builtin_amdgcn_mfma_f32_16x16x32_bf16(aF[m], bF[n],
                                                            acc[m][n], 0, 0, 0);
    __builtin_amdgcn_s_setprio(0);
  }

  // epilogue: C/D layout col=lane&15, row=(lane>>4)*4+r  [m89-verified]
  const int cl = lane & 15, rg4 = (lane >> 4) * 4;
#pragma unroll
  for (int m = 0; m < 8; ++m) {
#pragma unroll
    for (int n = 0; n < 4; ++n) {
      const int gcol = n0 + wc * 64 + n * 16 + cl;
      const float bv = HAS_BIAS ? bias[gcol] : 0.0f;
#pragma unroll
      for (int r = 0; r < 4; ++r) {
        const int grow = m0 + wr * 128 + m * 16 + rg4 + r;
        const float v = acc[m][n][r] * scale + bv;
        if (OUT_BF16)
          ((u16*)Cv)[(size_t)z * csb + (size_t)grow * ldc + gcol] = f2b(v);
        else
          ((float*)Cv)[(size_t)z * csb + (size_t)grow * ldc + gcol] = v;
      }
    }
  }
#undef STAGE
}

// ---------- launch ----------
extern "C" void kernel_launch(void* const* d_in, const int* in_sizes, int n_in,
                              void* d_out, int out_size, void* d_ws, size_t ws_size,
                              hipStream_t stream) {
  const float* x    = (const float*)d_in[0];
  const float* Wqkv = (const float*)d_in[1];
  const float* bqkv = (const float*)d_in[2];
  const float* Wout = (const float*)d_in[3];
  const float* bout = (const float*)d_in[4];
  float* out = (float*)d_out;

  char* ws = (char*)d_ws;
  const size_t NX = 16384ull * 1024;
  const size_t FIXED = 176160768ull;  // qkv 96MB + vT 32 + ctx 32 + w 8

  int c;
  if      (ws_size >= 134217728ull + FIXED) c = 4;
  else if (ws_size >=  67108864ull + FIXED) c = 2;
  else if (ws_size >=  33554432ull + FIXED) c = 1;
  else return;
  const size_t S0 = (size_t)c * 33554432ull;

  u16* xb    = (u16*)(ws);                       // dead before sc is written
  u16* sc    = (u16*)(ws);
  u16* qkvb  = (u16*)(ws + S0);
  u16* vT    = (u16*)(ws + S0 + 100663296ull);
  u16* ctxb  = (u16*)(ws + S0 + 134217728ull);
  u16* wqkvb = (u16*)(ws + S0 + 167772160ull);
  u16* woutb = (u16*)(ws + S0 + 174063616ull);

  cast_f32_bf16<<<dim3((int)(NX / 2048)), 256, 0, stream>>>(x, xb, (int)NX);
  cast_f32_bf16<<<dim3(1536), 256, 0, stream>>>(Wqkv, wqkvb, 3072 * 1024);
  cast_f32_bf16<<<dim3(512),  256, 0, stream>>>(Wout, woutb, 1024 * 1024);

  // qkv = x @ Wqkv^T + bqkv : M=16384 N=3072 K=1024, grid 768, gy=12
  gemm256<1, 1><<<dim3(768, 1), 512, 0, stream>>>(
      xb, wqkvb, qkvb, bqkv, 1024, 1024, 1024, 3072, 0, 0, 0, 1.0f, 12);

  transpose_v<<<dim3(128, 32, 4), 256, 0, stream>>>(qkvb, vT);

  for (int b0 = 0; b0 < 4; b0 += c) {
    const u16* qb = qkvb + (size_t)b0 * 4096 * 3072;
    // scores = (q @ k^T)/32 : M=N=4096 K=1024, grid 256 x c, gy=16
    gemm256<1, 0><<<dim3(256, c), 512, 0, stream>>>(
        qb, qb + 1024, sc, nullptr, 1024, 3072, 3072, 4096,
        4096L * 3072, 4096L * 3072, 4096L * 4096, 0.03125f, 16);
    softmax_rows<<<dim3(4096 * c), 256, 0, stream>>>(sc);
    // ctx = attn @ vT^T : M=4096 N=1024 K=4096, grid 64 x c, gy=4
    gemm256<1, 0><<<dim3(64, c), 512, 0, stream>>>(
        sc, vT + (size_t)b0 * 1024 * 4096, ctxb + (size_t)b0 * 4096 * 1024,
        nullptr, 4096, 4096, 4096, 1024,
        4096L * 4096, 1024L * 4096, 4096L * 1024, 1.0f, 4);
  }

  // out = ctx @ Wout^T + bout : M=16384 N=1024 K=1024, grid 256, gy=4
  gemm256<0, 1><<<dim3(256, 1), 512, 0, stream>>>(
      ctxb, woutb, out, bout, 1024, 1024, 1024, 1024, 0, 0, 0, 1.0f, 4);
}